// Round 11
// baseline (546.710 us; speedup 1.0000x reference)
//
#include <hip/hip_runtime.h>

// ---------------------------------------------------------------------------
// GCN pipeline, round 11 (7 dispatches, NO per-node CSR):
//   histA -> scanTiles -> multisplit2 (coarse counting sort + folded base
//   scan) -> prep (per-bucket deg->dinv,y; no scatter) -> aggL1 (bucket-LDS
//   float-atomic 5-dim aggregate -> z) -> transform12 (fused W1/relu/W2) ->
//   aggL2_fc (bucket-LDS atomic 32-dim aggregate + out2 + FC head).
// Round-10 lesson: place_fine2's srcs scatter + agg2_fc's sidx restage exist
// only to serve a per-node CSR. Bucket-sorted binned + per-bucket LDS
// ds_add_f32 accumulators make the CSR unnecessary. 1024-thr blocks on the
// 391-block bucket grids keep 16 waves/block for latency hiding (round-9
// lesson: don't starve a latency-bound gather of waves).
// ---------------------------------------------------------------------------

#define MS_TILE 2048
#define MAXB 512  // padded coarse-bucket count (NBkt = ceil(n/256) <= 512)

// per-tile LDS histogram of dst>>8 -> histG[tile*512 + b] (coalesced rows)
__global__ __launch_bounds__(256) void histA(const int* __restrict__ dst,
                                             int* __restrict__ histG, int E) {
    __shared__ int h[MAXB];
    int t = threadIdx.x;
    h[t] = 0;
    h[t + 256] = 0;
    __syncthreads();
    int base = blockIdx.x * MS_TILE;
    int cnt = min(MS_TILE, E - base);
    for (int k = t; k < cnt; k += 256) atomicAdd(&h[dst[base + k] >> 8], 1);
    __syncthreads();
    histG[blockIdx.x * MAXB + t] = h[t];
    histG[blockIdx.x * MAXB + 256 + t] = h[t + 256];
}

// one block per bucket b: exclusive scan of histG[.][b] across tiles ->
// offsG[tile*512+b]; bucket total -> bucketTotal[b]
__global__ __launch_bounds__(256) void scanTiles(const int* __restrict__ histG,
                                                 int* __restrict__ offsG,
                                                 int* __restrict__ bucketTotal,
                                                 int nTiles) {
    __shared__ int scn[256];
    int b = blockIdx.x, t = threadIdx.x;
    int run = 0;
    for (int base = 0; base < nTiles; base += 256) {
        int idx = base + t;
        int v = (idx < nTiles) ? histG[idx * MAXB + b] : 0;
        scn[t] = v;
        __syncthreads();
        int incl = v;
        for (int d = 1; d < 256; d <<= 1) {
            int add = (t >= d) ? scn[t - d] : 0;
            __syncthreads();
            incl += add;
            scn[t] = incl;
            __syncthreads();
        }
        if (idx < nTiles) offsG[idx * MAXB + b] = incl - v + run;
        run += scn[255];
        __syncthreads();
    }
    if (t == 0) bucketTotal[b] = run;
}

// Deterministic tile counting-sort. Payload: (src<<8)|(dst&255).
// Also scans bucketTotal -> global bucket bases; tile 0 publishes gbase.
__global__ __launch_bounds__(256) void multisplit2(
    const int* __restrict__ src, const int* __restrict__ dst,
    const int* __restrict__ histG, const int* __restrict__ offsG,
    const int* __restrict__ btot, int* __restrict__ gbaseOut,
    unsigned* __restrict__ binned, int E) {
    __shared__ unsigned stage[MS_TILE];
    __shared__ unsigned short sb[MS_TILE];
    __shared__ int hoff[MAXB + 1];
    __shared__ int hcur[MAXB];
    __shared__ int gb[MAXB];
    __shared__ int scn[256];
    int t = threadIdx.x;
    int tile = blockIdx.x;
    int base = tile * MS_TILE;
    int cnt = min(MS_TILE, E - base);

    // scan 1: bucket totals -> global bucket bases
    int b0 = btot[2 * t], b1v = btot[2 * t + 1];
    int s2 = b0 + b1v;
    scn[t] = s2;
    __syncthreads();
    int incl2 = s2;
    for (int d = 1; d < 256; d <<= 1) {
        int add = (t >= d) ? scn[t - d] : 0;
        __syncthreads();
        incl2 += add;
        scn[t] = incl2;
        __syncthreads();
    }
    int ex2 = incl2 - s2;
    gb[2 * t] = ex2 + offsG[tile * MAXB + 2 * t];
    gb[2 * t + 1] = ex2 + b0 + offsG[tile * MAXB + 2 * t + 1];
    if (tile == 0) {
        gbaseOut[2 * t] = ex2;
        gbaseOut[2 * t + 1] = ex2 + b0;
        if (t == 255) gbaseOut[MAXB] = E;
    }

    // scan 2: per-tile hist -> LDS stage layout
    int a0 = histG[tile * MAXB + 2 * t];
    int a1 = histG[tile * MAXB + 2 * t + 1];
    int s = a0 + a1;
    scn[t] = s;
    __syncthreads();
    int incl = s;
    for (int d = 1; d < 256; d <<= 1) {
        int add = (t >= d) ? scn[t - d] : 0;
        __syncthreads();
        incl += add;
        scn[t] = incl;
        __syncthreads();
    }
    int ex = incl - s;
    hoff[2 * t] = ex;
    hoff[2 * t + 1] = ex + a0;
    hcur[2 * t] = ex;
    hcur[2 * t + 1] = ex + a0;
    if (t == 255) hoff[MAXB] = cnt;
    __syncthreads();
    for (int k = t; k < cnt; k += 256) {
        int d = dst[base + k];
        int b = d >> 8;
        int p = atomicAdd(&hcur[b], 1);
        stage[p] = ((unsigned)src[base + k] << 8) | (unsigned)(d & 255);
        sb[p] = (unsigned short)b;
    }
    __syncthreads();
    for (int k = t; k < cnt; k += 256) {
        int b = sb[k];
        binned[gb[b] + (k - hoff[b])] = stage[k];
    }
}

// Per coarse bucket: deg via LDS count -> dinv, y = dinv*x (8-padded).
// No offsets, no cursor scatter (CSR eliminated).
__global__ __launch_bounds__(256) void prep(
    const unsigned* __restrict__ binned, const int* __restrict__ gbase,
    const float* __restrict__ x, float* __restrict__ dinv,
    float* __restrict__ y, int n) {
    __shared__ int cnt[256];
    int t = threadIdx.x, b = blockIdx.x;
    int node0 = b << 8;
    int nn = min(256, n - node0);
    int e0 = gbase[b], e1 = gbase[b + 1];
    cnt[t] = 0;
    __syncthreads();
    for (int k = e0 + t; k < e1; k += 256) atomicAdd(&cnt[binned[k] & 255u], 1);
    __syncthreads();
    if (t < nn) {
        int node = node0 + t;
        float di = 1.0f / sqrtf((float)(cnt[t] + 1));  // +1 self loop
        dinv[node] = di;
        const float* xr = x + (size_t)node * 5;
        float4 a = {xr[0] * di, xr[1] * di, xr[2] * di, xr[3] * di};
        float4 bq = {xr[4] * di, 0.f, 0.f, 0.f};
        *(float4*)(y + (size_t)node * 8) = a;
        *(float4*)(y + (size_t)node * 8 + 4) = bq;
    }
}

// Layer-1 aggregate in 5-dim space, bucket-LDS-atomic.
// z[i,:] = dinv[i]*(y[i,:] + sum_{e:dst=i} y[src,:]).
__global__ __launch_bounds__(1024) void aggL1(
    const unsigned* __restrict__ binned, const int* __restrict__ gbase,
    const float* __restrict__ y, const float* __restrict__ dinv,
    float* __restrict__ z, int n) {
    __shared__ float acc[256 * 9];  // stride 9; slots 5..7 stay 0
    int t = threadIdx.x, b = blockIdx.x;
    int node0 = b << 8;
    for (int idx = t; idx < 256 * 9; idx += 1024) acc[idx] = 0.f;
    __syncthreads();
    int e0 = gbase[b], e1 = gbase[b + 1];
    const float4* yv = (const float4*)y;
    for (int k = e0 + t; k < e1; k += 1024) {
        unsigned w = binned[k];
        int dl = (int)(w & 255u);
        int s = (int)(w >> 8);
        float4 v0 = yv[(size_t)s * 2];
        float v4 = y[(size_t)s * 8 + 4];
        float* a = acc + dl * 9;
        atomicAdd(a + 0, v0.x);
        atomicAdd(a + 1, v0.y);
        atomicAdd(a + 2, v0.z);
        atomicAdd(a + 3, v0.w);
        atomicAdd(a + 4, v4);
    }
    __syncthreads();
    // epilogue: 256 nodes x 2 float4s
    for (int idx = t; idx < 512; idx += 1024) {
        int ln = idx >> 1, h = idx & 1;
        int i = node0 + ln;
        if (i < n) {
            float di = dinv[i];
            float4 ys = yv[(size_t)i * 2 + h];
            const float* a = acc + ln * 9 + h * 4;
            float4 o = {di * (ys.x + a[0]), di * (ys.y + a[1]),
                        di * (ys.z + a[2]), di * (ys.w + a[3])};
            ((float4*)z)[(size_t)i * 2 + h] = o;
        }
    }
}

// FUSED transforms: out1 = relu(z@W1 + b1) kept in LDS; h2' = dinv*(out1@W2).
__global__ __launch_bounds__(256) void transform12(
    const float* __restrict__ z, const float* __restrict__ W1,
    const float* __restrict__ b1, const float* __restrict__ W2,
    const float* __restrict__ dinv, float* __restrict__ h2, int n) {
    __shared__ float w1s[320];
    __shared__ float b1s[64];
    __shared__ float w2s[64 * 32];
    __shared__ float o1[32 * 64];
    int t = threadIdx.x;
    w1s[t] = W1[t];
    if (t < 64) {
        w1s[t + 256] = W1[t + 256];
        b1s[t] = b1[t];
    }
#pragma unroll
    for (int r = 0; r < 8; ++r) w2s[r * 256 + t] = W2[r * 256 + t];
    __syncthreads();
    int node0 = blockIdx.x * 32;
#pragma unroll
    for (int r = 0; r < 8; ++r) {
        int idx = r * 256 + t;
        int li = idx >> 6, f = idx & 63;
        int i = node0 + li;
        if (i < n) {
            const float* zr = z + (size_t)i * 8;
            float acc = b1s[f];
#pragma unroll
            for (int k = 0; k < 5; ++k) acc += zr[k] * w1s[k * 64 + f];
            o1[li * 64 + f] = fmaxf(acc, 0.0f);
        }
    }
    __syncthreads();
#pragma unroll
    for (int r = 0; r < 4; ++r) {
        int idx = r * 256 + t;
        int li = idx >> 5, g = idx & 31;
        int i = node0 + li;
        if (i < n) {
            float acc = 0.f;
#pragma unroll
            for (int k = 0; k < 64; ++k) acc += o1[li * 64 + k] * w2s[k * 32 + g];
            h2[(size_t)i * 32 + g] = acc * dinv[i];
        }
    }
}

// Layer-2 aggregate + out2 + FC head, bucket-LDS-atomic. 8 lanes per edge
// gather one coalesced 128B h2' row; stride-33 acc keeps FC reads clean.
__global__ __launch_bounds__(1024) void aggL2_fc(
    const unsigned* __restrict__ binned, const int* __restrict__ gbase,
    const float* __restrict__ h2, const float* __restrict__ dinv,
    const float* __restrict__ b2, const float* __restrict__ fcW1,
    const float* __restrict__ fcb1, const float* __restrict__ fcW2,
    const float* __restrict__ fcb2, float* __restrict__ out, int n) {
    __shared__ float sm[256 * 33];   // acc / out2, stride-33 padded
    __shared__ float x3s[256 * 16];
    __shared__ float w1s[512];
    __shared__ float w2s[32];
    __shared__ float b1s[16];
    __shared__ float b2s[2];
    __shared__ float bs2[32];
    int t = threadIdx.x, b = blockIdx.x;
    int node0 = b << 8;
    if (t < 512) w1s[t] = fcW1[t];
    else if (t < 544) w2s[t - 512] = fcW2[t - 512];
    else if (t < 560) b1s[t - 544] = fcb1[t - 544];
    else if (t < 562) b2s[t - 560] = fcb2[t - 560];
    else if (t < 594) bs2[t - 562] = b2[t - 562];
    for (int idx = t; idx < 256 * 33; idx += 1024) sm[idx] = 0.f;
    __syncthreads();

    int e0 = gbase[b], e1 = gbase[b + 1];
    int g = t >> 3, l8 = t & 7;
    const float4* h2v = (const float4*)h2;
    for (int k = e0 + g; k < e1; k += 128) {
        unsigned w = binned[k];
        int dl = (int)(w & 255u);
        int s = (int)(w >> 8);
        float4 v = h2v[(size_t)s * 8 + l8];
        float* a = sm + dl * 33 + l8 * 4;
        atomicAdd(a + 0, v.x);
        atomicAdd(a + 1, v.y);
        atomicAdd(a + 2, v.z);
        atomicAdd(a + 3, v.w);
    }
    __syncthreads();
    // out2 = relu(dinv*(h2_self + acc) + b2), in place in sm
    for (int idx = t; idx < 256 * 32; idx += 1024) {
        int ln = idx >> 5, f = idx & 31;
        int i = node0 + ln;
        if (i < n) {
            float v = dinv[i] * (h2[(size_t)i * 32 + f] + sm[ln * 33 + f]) + bs2[f];
            sm[ln * 33 + f] = fmaxf(v, 0.f);
        }
    }
    __syncthreads();
    // x3 = relu(out2 @ fcW1 + fcb1): 256 nodes x 16
#pragma unroll
    for (int r = 0; r < 4; ++r) {
        int idx = r * 1024 + t;
        int lj = idx >> 4, j = idx & 15;
        if (node0 + lj < n) {
            float a = b1s[j];
#pragma unroll
            for (int k = 0; k < 32; ++k) a += sm[lj * 33 + k] * w1s[k * 16 + j];
            x3s[lj * 16 + j] = fmaxf(a, 0.f);
        }
    }
    __syncthreads();
    // out = x3 @ fcW2 + fcb2: 256 nodes x 2 (coalesced 2KB store)
    if (t < 512) {
        int lj = t >> 1, o = t & 1;
        if (node0 + lj < n) {
            float a = b2s[o];
#pragma unroll
            for (int j = 0; j < 16; ++j) a += x3s[lj * 16 + j] * w2s[j * 2 + o];
            out[(size_t)(node0 + lj) * 2 + o] = a;
        }
    }
}

extern "C" void kernel_launch(void* const* d_in, const int* in_sizes, int n_in,
                              void* d_out, int out_size, void* d_ws, size_t ws_size,
                              hipStream_t stream) {
    const float* edge_attr = (const float*)d_in[0];
    const int* edge_index  = (const int*)d_in[1];
    const float* W1   = (const float*)d_in[2];
    const float* b1   = (const float*)d_in[3];
    const float* W2   = (const float*)d_in[4];
    const float* b2   = (const float*)d_in[5];
    const float* fcW1 = (const float*)d_in[6];
    const float* fcb1 = (const float*)d_in[7];
    const float* fcW2 = (const float*)d_in[8];
    const float* fcb2 = (const float*)d_in[9];
    float* out = (float*)d_out;

    int n = in_sizes[0] / 5;
    int E = in_sizes[1] / 2;
    int NBkt = (n + 255) >> 8;                 // 391 for n=100000 (<= MAXB)
    int nTiles = (E + MS_TILE - 1) / MS_TILE;  // 782
    const int* src = edge_index;
    const int* dst = edge_index + E;

    char* ws = (char*)d_ws;
    auto alloc = [&](size_t bytes) {
        char* p = ws;
        ws += (bytes + 255) & ~(size_t)255;
        return p;
    };
    float*    dinv   = (float*)alloc((size_t)n * 4);
    int*      histG  = (int*)alloc((size_t)nTiles * MAXB * 4);
    int*      offsG  = (int*)alloc((size_t)nTiles * MAXB * 4);
    int*      btot   = (int*)alloc((size_t)MAXB * 4);
    int*      gbase  = (int*)alloc((size_t)(MAXB + 1) * 4);
    unsigned* binned = (unsigned*)alloc((size_t)E * 4);
    float*    y      = (float*)alloc((size_t)n * 8 * 4);
    float*    z      = (float*)alloc((size_t)n * 8 * 4);
    float*    h2     = (float*)alloc((size_t)n * 32 * 4);

    histA<<<nTiles, 256, 0, stream>>>(dst, histG, E);
    scanTiles<<<MAXB, 256, 0, stream>>>(histG, offsG, btot, nTiles);
    multisplit2<<<nTiles, 256, 0, stream>>>(src, dst, histG, offsG, btot, gbase,
                                            binned, E);
    prep<<<NBkt, 256, 0, stream>>>(binned, gbase, edge_attr, dinv, y, n);
    aggL1<<<NBkt, 1024, 0, stream>>>(binned, gbase, y, dinv, z, n);
    transform12<<<(n + 31) / 32, 256, 0, stream>>>(z, W1, b1, W2, dinv, h2, n);
    aggL2_fc<<<NBkt, 1024, 0, stream>>>(binned, gbase, h2, dinv, b2,
                                        fcW1, fcb1, fcW2, fcb2, out, n);
}

// Round 12
// 198.294 us; speedup vs baseline: 2.7571x; 2.7571x over previous
//
#include <hip/hip_runtime.h>

// ---------------------------------------------------------------------------
// GCN pipeline, round 12 (= round-10 structure, deg array eliminated):
//   histA -> scanTiles -> multisplit2 (counting sort + folded bucket-base
//   scan) -> place_fine2 (per-node CSR offs + dinv + y) -> agg_xin
//   (independent-thread 5-dim aggregate) -> transform12 (fused W1/relu/W2)
//   -> agg2_fc (layer-2 aggregate + FC head, LDS-staged indices).
// Round-11 lesson (51M LDS atomicAdds = 356us, 2.7x total regression):
// LDS float atomics are NOT a viable aggregation primitive at deg~16 —
// the CSR + private register accumulation (this structure) is the right
// shape. deg[] removed: cnt = offs[i+1]-offs[i] (sentinel E).
// ---------------------------------------------------------------------------

#define MS_TILE 2048
#define MAXB 512  // padded coarse-bucket count (NBkt = ceil(n/256) <= 512)
#define AGG_NODES 32
#define AGG_STAGE 1024

// per-tile LDS histogram of dst>>8 -> histG[tile*512 + b] (coalesced rows)
__global__ __launch_bounds__(256) void histA(const int* __restrict__ dst,
                                             int* __restrict__ histG, int E) {
    __shared__ int h[MAXB];
    int t = threadIdx.x;
    h[t] = 0;
    h[t + 256] = 0;
    __syncthreads();
    int base = blockIdx.x * MS_TILE;
    int cnt = min(MS_TILE, E - base);
    for (int k = t; k < cnt; k += 256) atomicAdd(&h[dst[base + k] >> 8], 1);
    __syncthreads();
    histG[blockIdx.x * MAXB + t] = h[t];
    histG[blockIdx.x * MAXB + 256 + t] = h[t + 256];
}

// one block per bucket b: exclusive scan of histG[.][b] across tiles ->
// offsG[tile*512+b]; bucket total -> bucketTotal[b]
__global__ __launch_bounds__(256) void scanTiles(const int* __restrict__ histG,
                                                 int* __restrict__ offsG,
                                                 int* __restrict__ bucketTotal,
                                                 int nTiles) {
    __shared__ int scn[256];
    int b = blockIdx.x, t = threadIdx.x;
    int run = 0;
    for (int base = 0; base < nTiles; base += 256) {
        int idx = base + t;
        int v = (idx < nTiles) ? histG[idx * MAXB + b] : 0;
        scn[t] = v;
        __syncthreads();
        int incl = v;
        for (int d = 1; d < 256; d <<= 1) {
            int add = (t >= d) ? scn[t - d] : 0;
            __syncthreads();
            incl += add;
            scn[t] = incl;
            __syncthreads();
        }
        if (idx < nTiles) offsG[idx * MAXB + b] = incl - v + run;
        run += scn[255];
        __syncthreads();
    }
    if (t == 0) bucketTotal[b] = run;
}

// Deterministic tile counting-sort. Payload: (src<<8)|(dst&255).
// Also scans bucketTotal -> global bucket bases; tile 0 publishes gbase.
__global__ __launch_bounds__(256) void multisplit2(
    const int* __restrict__ src, const int* __restrict__ dst,
    const int* __restrict__ histG, const int* __restrict__ offsG,
    const int* __restrict__ btot, int* __restrict__ gbaseOut,
    unsigned* __restrict__ binned, int E) {
    __shared__ unsigned stage[MS_TILE];
    __shared__ unsigned short sb[MS_TILE];
    __shared__ int hoff[MAXB + 1];
    __shared__ int hcur[MAXB];
    __shared__ int gb[MAXB];
    __shared__ int scn[256];
    int t = threadIdx.x;
    int tile = blockIdx.x;
    int base = tile * MS_TILE;
    int cnt = min(MS_TILE, E - base);

    // scan 1: bucket totals -> global bucket bases
    int b0 = btot[2 * t], b1v = btot[2 * t + 1];
    int s2 = b0 + b1v;
    scn[t] = s2;
    __syncthreads();
    int incl2 = s2;
    for (int d = 1; d < 256; d <<= 1) {
        int add = (t >= d) ? scn[t - d] : 0;
        __syncthreads();
        incl2 += add;
        scn[t] = incl2;
        __syncthreads();
    }
    int ex2 = incl2 - s2;
    gb[2 * t] = ex2 + offsG[tile * MAXB + 2 * t];
    gb[2 * t + 1] = ex2 + b0 + offsG[tile * MAXB + 2 * t + 1];
    if (tile == 0) {
        gbaseOut[2 * t] = ex2;
        gbaseOut[2 * t + 1] = ex2 + b0;
        if (t == 255) gbaseOut[MAXB] = E;
    }

    // scan 2: per-tile hist -> LDS stage layout
    int a0 = histG[tile * MAXB + 2 * t];
    int a1 = histG[tile * MAXB + 2 * t + 1];
    int s = a0 + a1;
    scn[t] = s;
    __syncthreads();
    int incl = s;
    for (int d = 1; d < 256; d <<= 1) {
        int add = (t >= d) ? scn[t - d] : 0;
        __syncthreads();
        incl += add;
        scn[t] = incl;
        __syncthreads();
    }
    int ex = incl - s;
    hoff[2 * t] = ex;
    hoff[2 * t + 1] = ex + a0;
    hcur[2 * t] = ex;
    hcur[2 * t + 1] = ex + a0;
    if (t == 255) hoff[MAXB] = cnt;
    __syncthreads();
    for (int k = t; k < cnt; k += 256) {
        int d = dst[base + k];
        int b = d >> 8;
        int p = atomicAdd(&hcur[b], 1);
        stage[p] = ((unsigned)src[base + k] << 8) | (unsigned)(d & 255);
        sb[p] = (unsigned short)b;
    }
    __syncthreads();
    for (int k = t; k < cnt; k += 256) {
        int b = sb[k];
        binned[gb[b] + (k - hoff[b])] = stage[k];
    }
}

// Per coarse bucket: per-node deg via LDS count, LDS scan -> offs, dinv,
// y[i,:] = dinv[i]*x[i,:] (padded to 8 floats), then exact CSR scatter.
__global__ __launch_bounds__(256) void place_fine2(
    const unsigned* __restrict__ binned, const int* __restrict__ gbase,
    const float* __restrict__ x, int* __restrict__ offs,
    float* __restrict__ dinv, float* __restrict__ y, int* __restrict__ srcs, int n) {
    __shared__ int cnt[256];
    __shared__ int scn[256];
    __shared__ int lcur[256];
    int t = threadIdx.x, b = blockIdx.x;
    int node0 = b << 8;
    int nn = min(256, n - node0);
    int e0 = gbase[b], e1 = gbase[b + 1];
    cnt[t] = 0;
    __syncthreads();
    for (int k = e0 + t; k < e1; k += 256) atomicAdd(&cnt[binned[k] & 255u], 1);
    __syncthreads();
    int c = cnt[t];
    scn[t] = c;
    __syncthreads();
    int incl = c;
    for (int d = 1; d < 256; d <<= 1) {
        int add = (t >= d) ? scn[t - d] : 0;
        __syncthreads();
        incl += add;
        scn[t] = incl;
        __syncthreads();
    }
    int myoff = e0 + (incl - c);
    lcur[t] = myoff;
    if (t < nn) {
        int node = node0 + t;
        offs[node] = myoff;
        float di = 1.0f / sqrtf((float)(c + 1));  // +1 self loop
        dinv[node] = di;
        const float* xr = x + (size_t)node * 5;
        float4 a = {xr[0] * di, xr[1] * di, xr[2] * di, xr[3] * di};
        float4 bq = {xr[4] * di, 0.f, 0.f, 0.f};
        *(float4*)(y + (size_t)node * 8) = a;
        *(float4*)(y + (size_t)node * 8 + 4) = bq;
    }
    __syncthreads();
    for (int k = e0 + t; k < e1; k += 256) {
        unsigned w = binned[k];
        int p = atomicAdd(&lcur[w & 255u], 1);
        srcs[p] = (int)(w >> 8);
    }
}

// z[i,:] = dinv[i]*(y[i,:] + sum_{e:dst=i} y[src,:])  (8-float padded rows,
// 3.2MB working set -> L2-resident random gathers). Independent threads,
// 128-thr blocks (782 blocks), 4-edge unroll = 8 float4 loads in flight.
__global__ __launch_bounds__(128) void agg_xin(
    const float* __restrict__ y, const int* __restrict__ srcs,
    const int* __restrict__ offs, const float* __restrict__ dinv,
    float* __restrict__ z, int n, int E) {
    int i = blockIdx.x * 128 + threadIdx.x;
    if (i >= n) return;
    const float4* yv = (const float4*)y;
    float4 a = yv[(size_t)i * 2];
    float4 b = yv[(size_t)i * 2 + 1];
    int off = offs[i];
    int cnt = ((i + 1 < n) ? offs[i + 1] : E) - off;
    int p = 0;
    for (; p + 4 <= cnt; p += 4) {
        int s0 = srcs[off + p], s1 = srcs[off + p + 1];
        int s2 = srcs[off + p + 2], s3 = srcs[off + p + 3];
        float4 v0 = yv[(size_t)s0 * 2];
        float4 w0 = yv[(size_t)s0 * 2 + 1];
        float4 v1 = yv[(size_t)s1 * 2];
        float4 w1 = yv[(size_t)s1 * 2 + 1];
        float4 v2 = yv[(size_t)s2 * 2];
        float4 w2 = yv[(size_t)s2 * 2 + 1];
        float4 v3 = yv[(size_t)s3 * 2];
        float4 w3 = yv[(size_t)s3 * 2 + 1];
        a.x += (v0.x + v1.x) + (v2.x + v3.x);
        a.y += (v0.y + v1.y) + (v2.y + v3.y);
        a.z += (v0.z + v1.z) + (v2.z + v3.z);
        a.w += (v0.w + v1.w) + (v2.w + v3.w);
        b.x += (w0.x + w1.x) + (w2.x + w3.x);
    }
    for (; p < cnt; ++p) {
        int s0 = srcs[off + p];
        float4 v0 = yv[(size_t)s0 * 2];
        float w0 = y[(size_t)s0 * 8 + 4];
        a.x += v0.x; a.y += v0.y; a.z += v0.z; a.w += v0.w;
        b.x += w0;
    }
    float di = dinv[i];
    float4 oa = {a.x * di, a.y * di, a.z * di, a.w * di};
    float4 ob = {b.x * di, 0.f, 0.f, 0.f};
    float4* zv = (float4*)z;
    zv[(size_t)i * 2] = oa;
    zv[(size_t)i * 2 + 1] = ob;
}

// FUSED transforms: out1 = relu(z@W1 + b1) kept in LDS; h2' = dinv*(out1@W2).
__global__ __launch_bounds__(256) void transform12(
    const float* __restrict__ z, const float* __restrict__ W1,
    const float* __restrict__ b1, const float* __restrict__ W2,
    const float* __restrict__ dinv, float* __restrict__ h2, int n) {
    __shared__ float w1s[320];
    __shared__ float b1s[64];
    __shared__ float w2s[64 * 32];
    __shared__ float o1[32 * 64];
    int t = threadIdx.x;
    w1s[t] = W1[t];
    if (t < 64) {
        w1s[t + 256] = W1[t + 256];
        b1s[t] = b1[t];
    }
#pragma unroll
    for (int r = 0; r < 8; ++r) w2s[r * 256 + t] = W2[r * 256 + t];
    __syncthreads();
    int node0 = blockIdx.x * 32;
#pragma unroll
    for (int r = 0; r < 8; ++r) {
        int idx = r * 256 + t;
        int li = idx >> 6, f = idx & 63;
        int i = node0 + li;
        if (i < n) {
            const float* zr = z + (size_t)i * 8;
            float acc = b1s[f];
#pragma unroll
            for (int k = 0; k < 5; ++k) acc += zr[k] * w1s[k * 64 + f];
            o1[li * 64 + f] = fmaxf(acc, 0.0f);
        }
    }
    __syncthreads();
#pragma unroll
    for (int r = 0; r < 4; ++r) {
        int idx = r * 256 + t;
        int li = idx >> 5, g = idx & 31;
        int i = node0 + li;
        if (i < n) {
            float acc = 0.f;
#pragma unroll
            for (int k = 0; k < 64; ++k) acc += o1[li * 64 + k] * w2s[k * 32 + g];
            h2[(size_t)i * 32 + g] = acc * dinv[i];
        }
    }
}

// FUSED layer-2 aggregate + FC head. Block = 32 nodes x 8 f4-groups;
// LDS-staged CSR indices (byte offsets), 8-deep float4 gather unroll.
__global__ __launch_bounds__(256) void agg2_fc(
    const float* __restrict__ h, const int* __restrict__ srcs,
    const int* __restrict__ offs, const float* __restrict__ dinv,
    const float* __restrict__ b2, const float* __restrict__ fcW1,
    const float* __restrict__ fcb1, const float* __restrict__ fcW2,
    const float* __restrict__ fcb2, float* __restrict__ out, int n, int E) {
    __shared__ int sidx[AGG_STAGE];
    __shared__ float sm[AGG_NODES * 33];  // out2, stride-33 padded
    __shared__ float x3s[AGG_NODES * 16];
    __shared__ float w1s[512];
    __shared__ float w2s[32];
    __shared__ float b1s[16];
    __shared__ float b2s[2];
    __shared__ float bs2[32];
    int t = threadIdx.x;
    w1s[t] = fcW1[t];
    w1s[t + 256] = fcW1[t + 256];
    if (t < 32) { w2s[t] = fcW2[t]; bs2[t] = b2[t]; }
    if (t < 16) b1s[t] = fcb1[t];
    if (t < 2) b2s[t] = fcb2[t];

    int node0 = blockIdx.x * AGG_NODES;
    int li = t >> 3, fq = t & 7;  // node-in-block, 4-feature group
    int i = node0 + li;
    bool live = (i < n);
    const char* hb = (const char*)h;

    int e0 = offs[node0];
    int eEnd = (node0 + AGG_NODES < n) ? offs[node0 + AGG_NODES] : E;
    int myOff = 0, myCnt = 0;
    float4 acc = {0.f, 0.f, 0.f, 0.f};
    if (live) {
        myOff = offs[i];
        myCnt = ((i + 1 < n) ? offs[i + 1] : E) - myOff;
        acc = *(const float4*)(hb + ((size_t)i << 7) + (fq << 4));  // self-loop
    }

    for (int cs = e0; cs < eEnd; cs += AGG_STAGE) {
        int ce = min(cs + AGG_STAGE, eEnd);
        for (int k = cs + t; k < ce; k += 256) sidx[k - cs] = srcs[k] << 7;
        __syncthreads();
        int ps = max(myOff, cs), pe = min(myOff + myCnt, ce);
        int p = ps;
        for (; p + 8 <= pe; p += 8) {
            int o[8];
#pragma unroll
            for (int u = 0; u < 8; ++u) o[u] = sidx[p + u - cs];
            float4 v[8];
#pragma unroll
            for (int u = 0; u < 8; ++u)
                v[u] = *(const float4*)(hb + o[u] + (fq << 4));
#pragma unroll
            for (int u = 0; u < 8; ++u) {
                acc.x += v[u].x; acc.y += v[u].y;
                acc.z += v[u].z; acc.w += v[u].w;
            }
        }
        for (; p + 4 <= pe; p += 4) {
            int o0 = sidx[p - cs], o1 = sidx[p + 1 - cs];
            int o2 = sidx[p + 2 - cs], o3 = sidx[p + 3 - cs];
            float4 v0 = *(const float4*)(hb + o0 + (fq << 4));
            float4 v1 = *(const float4*)(hb + o1 + (fq << 4));
            float4 v2 = *(const float4*)(hb + o2 + (fq << 4));
            float4 v3 = *(const float4*)(hb + o3 + (fq << 4));
            acc.x += (v0.x + v1.x) + (v2.x + v3.x);
            acc.y += (v0.y + v1.y) + (v2.y + v3.y);
            acc.z += (v0.z + v1.z) + (v2.z + v3.z);
            acc.w += (v0.w + v1.w) + (v2.w + v3.w);
        }
        for (; p < pe; ++p) {
            float4 v = *(const float4*)(hb + sidx[p - cs] + (fq << 4));
            acc.x += v.x; acc.y += v.y; acc.z += v.z; acc.w += v.w;
        }
        __syncthreads();
    }

    if (live) {
        float di = dinv[i];
        int f0 = fq << 2;
        sm[li * 33 + f0 + 0] = fmaxf(di * acc.x + bs2[f0 + 0], 0.f);
        sm[li * 33 + f0 + 1] = fmaxf(di * acc.y + bs2[f0 + 1], 0.f);
        sm[li * 33 + f0 + 2] = fmaxf(di * acc.z + bs2[f0 + 2], 0.f);
        sm[li * 33 + f0 + 3] = fmaxf(di * acc.w + bs2[f0 + 3], 0.f);
    }
    __syncthreads();
#pragma unroll
    for (int r = 0; r < 2; ++r) {
        int idx = r * 256 + t;
        int lj = idx >> 4, j = idx & 15;
        if (node0 + lj < n) {
            float a = b1s[j];
#pragma unroll
            for (int k = 0; k < 32; ++k) a += sm[lj * 33 + k] * w1s[k * 16 + j];
            x3s[lj * 16 + j] = fmaxf(a, 0.f);
        }
    }
    __syncthreads();
    if (t < 64) {
        int lj = t >> 1, o = t & 1;
        if (node0 + lj < n) {
            float a = b2s[o];
#pragma unroll
            for (int j = 0; j < 16; ++j) a += x3s[lj * 16 + j] * w2s[j * 2 + o];
            out[(size_t)(node0 + lj) * 2 + o] = a;
        }
    }
}

extern "C" void kernel_launch(void* const* d_in, const int* in_sizes, int n_in,
                              void* d_out, int out_size, void* d_ws, size_t ws_size,
                              hipStream_t stream) {
    const float* edge_attr = (const float*)d_in[0];
    const int* edge_index  = (const int*)d_in[1];
    const float* W1   = (const float*)d_in[2];
    const float* b1   = (const float*)d_in[3];
    const float* W2   = (const float*)d_in[4];
    const float* b2   = (const float*)d_in[5];
    const float* fcW1 = (const float*)d_in[6];
    const float* fcb1 = (const float*)d_in[7];
    const float* fcW2 = (const float*)d_in[8];
    const float* fcb2 = (const float*)d_in[9];
    float* out = (float*)d_out;

    int n = in_sizes[0] / 5;
    int E = in_sizes[1] / 2;
    int NBkt = (n + 255) >> 8;                 // 391 for n=100000 (<= MAXB)
    int nTiles = (E + MS_TILE - 1) / MS_TILE;  // 782
    const int* src = edge_index;
    const int* dst = edge_index + E;

    char* ws = (char*)d_ws;
    auto alloc = [&](size_t bytes) {
        char* p = ws;
        ws += (bytes + 255) & ~(size_t)255;
        return p;
    };
    int*      offs   = (int*)alloc((size_t)n * 4);
    float*    dinv   = (float*)alloc((size_t)n * 4);
    int*      histG  = (int*)alloc((size_t)nTiles * MAXB * 4);
    int*      offsG  = (int*)alloc((size_t)nTiles * MAXB * 4);
    int*      btot   = (int*)alloc((size_t)MAXB * 4);
    int*      gbase  = (int*)alloc((size_t)(MAXB + 1) * 4);
    int*      srcs   = (int*)alloc((size_t)E * 4);
    unsigned* binned = (unsigned*)alloc((size_t)E * 4);
    float*    y      = (float*)alloc((size_t)n * 8 * 4);
    float*    z      = (float*)alloc((size_t)n * 8 * 4);
    float*    h2     = (float*)alloc((size_t)n * 32 * 4);

    histA<<<nTiles, 256, 0, stream>>>(dst, histG, E);
    scanTiles<<<MAXB, 256, 0, stream>>>(histG, offsG, btot, nTiles);
    multisplit2<<<nTiles, 256, 0, stream>>>(src, dst, histG, offsG, btot, gbase,
                                            binned, E);
    place_fine2<<<NBkt, 256, 0, stream>>>(binned, gbase, edge_attr, offs, dinv,
                                          y, srcs, n);
    agg_xin<<<(n + 127) / 128, 128, 0, stream>>>(y, srcs, offs, dinv, z, n, E);
    transform12<<<(n + 31) / 32, 256, 0, stream>>>(z, W1, b1, W2, dinv, h2, n);
    agg2_fc<<<(n + AGG_NODES - 1) / AGG_NODES, 256, 0, stream>>>(
        h2, srcs, offs, dinv, b2, fcW1, fcb1, fcW2, fcb2, out, n, E);
}